// Round 7
// baseline (446.149 us; speedup 1.0000x reference)
//
#include <hip/hip_runtime.h>

// ---------------------------------------------------------------------------
// LayerStacks (NNUE-style) on MI355X.
//   h0 = clamp01( x @ (w0[b]+w_fact)^T + b0[b] )   // 1024 -> 32, bf16 MFMA
//   h1 = clamp01( h0 @ w1[b]^T + b1[b] )           // 32 -> 32,  fp32 VALU
//   out = h1 @ w2[b]^T + b2[b]                     // 32 -> 1,   fp32 VALU
// R4-R9 model update: dur tracks TOTAL vmem bytes (x + weight frags) at
// ~9 TB/s aggregate (~15 B/cyc/CU), across wildly different schedules
// (R9's wait-reordering: neutral). Weight frags were 4x the x bytes: every
// 32-row block re-read all 512 KB of wB from L2.
// R10: TILE=128 rows/block (512 blocks). Wave owns bucket-pair over full K
// with 4 row-tiles of accumulators (128 acc VGPRs); each chunk's 8 weight
// regs are reused across 4 row-tiles -> weight traffic 1.07 GB -> 262 MB,
// total vmem 1.34 GB -> ~530 MB. Same per-row math, same K order ->
// bit-identical output (absmax 0.005859375).
// ---------------------------------------------------------------------------

#define B_ROWS 65536
#define LK     1024       // 2*L1
#define TILE   128        // rows per block
#define NBLK   (B_ROWS / TILE)   // 512, exact
#define KC     64         // K-chunk in fp32 elems
#define NCH    (LK / KC)  // 16
#define SROW   136        // LDS bytes/row/chunk (128 bf16 data + 8 pad)
#define BUFSZ  (TILE * SROW)     // 17408

// ws layout (bytes):
//   [0, 524288)       : wB bf16 B-frags of (w0+w_fact): per bucket 4096 uint4;
//                       frag c*64+l = W[bkt*32 + (l&31)][16c + 8*(l>>5) .. +8]
//   [524288, 589824)  : bktg[65536] uchar per-row bucket
#define BKT_OFF 524288

typedef short  short8  __attribute__((ext_vector_type(8)));
typedef float  f32x16  __attribute__((ext_vector_type(16)));

__device__ __forceinline__ unsigned pkbf(float a, float b) {
    // round-to-nearest-even fp32 -> bf16, packed pair (bit-trick)
    unsigned ua = __float_as_uint(a), ub = __float_as_uint(b);
    ua = (ua + 0x7FFFu + ((ua >> 16) & 1u)) >> 16;
    ub = (ub + 0x7FFFu + ((ub >> 16) & 1u)) >> 16;
    return (ua & 0xFFFFu) | (ub << 16);
}

__device__ __forceinline__ unsigned cvtpk(float a, float b) {
    // RTNE fp32->bf16 packed pair, single instruction on gfx950
    unsigned r;
    asm("v_cvt_pk_bf16_f32 %0, %1, %2" : "=v"(r) : "v"(a), "v"(b));
    return r;
}

// ls_indices may be int32 or int64. If int64, the high words (odd int32
// slots) of the first 64 elements are all zero (values 0..7). Deterministic.
__device__ __forceinline__ bool detect_i64(const int* p) {
    int acc = 0;
#pragma unroll
    for (int i = 0; i < 64; ++i) acc |= p[2 * i + 1];
    return acc == 0;
}

__device__ __forceinline__ int load_bucket(const int* p, int r, bool i64) {
    return (i64 ? p[2 * r] : p[r]) & 7;
}

// --- K1: weight prep + bucket decode ----------------------------------------
// Blocks 0..31: build bf16 B-fragments of (w0+w_fact), 1 frag/thread.
// Block 32: decode ls_indices -> bktg[65536] uchar.
__global__ __launch_bounds__(1024) void k_prep(
    const int* __restrict__ idx, const float* __restrict__ w0,
    const float* __restrict__ wf, uint4* __restrict__ wB,
    unsigned char* __restrict__ bktg)
{
    int t = threadIdx.x;
    if (blockIdx.x == 32) {
        __shared__ int s_i64;
        if (t == 0) s_i64 = detect_i64(idx) ? 1 : 0;
        __syncthreads();
        bool i64 = (s_i64 != 0);
#pragma unroll 4
        for (int j = 0; j < 64; ++j)
            bktg[j * 1024 + t] = (unsigned char)load_bucket(idx, j * 1024 + t, i64);
        return;
    }
    int f = blockIdx.x * 1024 + t;             // 32768 frags
    int b   = f >> 12;
    int i12 = f & 4095;
    int kc  = i12 >> 8;
    int i8  = i12 & 255;
    int n   = i8 & 31;
    int khi = i8 >> 5;
    int k = kc * 64 + khi * 8;                 // == c*16 + 8*(lane>>5)
    const float* p0 = w0 + (size_t)(b * 32 + n) * LK + k;
    const float* pf = wf + (size_t)n * LK + k;
    float v[8];
#pragma unroll
    for (int j = 0; j < 8; ++j) v[j] = p0[j] + pf[j];
    uint4 o;
    o.x = pkbf(v[0], v[1]); o.y = pkbf(v[2], v[3]);
    o.z = pkbf(v[4], v[5]); o.w = pkbf(v[6], v[7]);
    wB[f] = o;
}

// --- K2: main fused kernel ---------------------------------------------------
// Block = 256 thr = 4 waves; 128 consecutive rows; K in 16 chunks of 64,
// LDS double-buffered. Per chunk: [batch 8 weight uint4 -> regs (2 buckets x
// 4 c-steps)] -> [issue 8 x-float4 prefetch] -> [4 row-tiles x 4 c x 2
// buckets MFMA; weight regs reused across row-tiles] -> [pack+write] ->
// barrier. Epilogue selects per-row bucket, layers 1+2 fp32 (2 thr/row).
__global__ __launch_bounds__(256, 2) void k_main(
    const float* __restrict__ x, const unsigned char* __restrict__ bktg,
    const uint4* __restrict__ wB, const float* __restrict__ b0,
    const float* __restrict__ w1, const float* __restrict__ b1,
    const float* __restrict__ w2, const float* __restrict__ b2,
    float* __restrict__ out)
{
    __shared__ __align__(16) unsigned char a_s[2 * BUFSZ];  // 34816 B
    __shared__ float hb[TILE * 36];                         // 18432 B
    __shared__ int   bkt_s[TILE];

    int row0 = blockIdx.x * TILE;
    int t    = threadIdx.x;
    int lane = t & 63;
    int wv   = t >> 6;
    int hi   = lane >> 5;
    int nn   = lane & 31;

    if (t < TILE) bkt_s[t] = (int)bktg[row0 + t];

    // staging geometry: chunk = 128 rows x 16 float4 (64 fp32/row).
    // flat f = 256q + t (q=0..7): row = 16q + (t>>4), col4 = t&15.
    const float4* gp = (const float4*)x + (size_t)(row0 + (t >> 4)) * 256 + (t & 15);
    const int wb_off = (t >> 4) * SROW + (t & 15) * 8;

    // ---- prologue: stage chunk 0 into buf0
    float4 v[8];
#pragma unroll
    for (int q = 0; q < 8; ++q) v[q] = gp[q * 4096];
#pragma unroll
    for (int q = 0; q < 8; ++q) {
        uint2 o; o.x = cvtpk(v[q].x, v[q].y); o.y = cvtpk(v[q].z, v[q].w);
        *(uint2*)(a_s + wb_off + q * (16 * SROW)) = o;
    }
    __syncthreads();

    const uint4* wB0 = wB + (size_t)(2 * wv) * 4096 + lane;
    const uint4* wB1 = wB0 + 4096;

    f32x16 acc0[4], acc1[4];
#pragma unroll
    for (int rt = 0; rt < 4; ++rt)
#pragma unroll
        for (int i = 0; i < 16; ++i) { acc0[rt][i] = 0.0f; acc1[rt][i] = 0.0f; }

    union UAB { uint4 u; short8 s8; };
    const int abase = (lane & 31) * SROW + 16 * hi;

    for (int ck = 0; ck < NCH; ++ck) {
        const unsigned char* cur = a_s + (ck & 1) * BUFSZ;
        unsigned char* nxt = a_s + ((ck + 1) & 1) * BUFSZ;

        // 1. batched weight loads: 2 buckets x 4 c-steps (one wait, reused 4x)
        UAB w0r[4], w1r[4];
#pragma unroll
        for (int cc = 0; cc < 4; ++cc) w0r[cc].u = wB0[(ck * 4 + cc) * 64];
#pragma unroll
        for (int cc = 0; cc < 4; ++cc) w1r[cc].u = wB1[(ck * 4 + cc) * 64];

        // 2. x prefetch for next chunk (newest in vmcnt queue, stays in flight)
        if (ck + 1 < NCH) {
#pragma unroll
            for (int q = 0; q < 8; ++q) v[q] = gp[q * 4096 + (ck + 1) * 16];
        }

        // 3. MFMA: 4 row-tiles x 4 c-steps x 2 buckets from LDS A + reg B
#pragma unroll
        for (int rt = 0; rt < 4; ++rt) {
            const unsigned char* Ab = cur + rt * (32 * SROW) + abase;
#pragma unroll
            for (int cc = 0; cc < 4; ++cc) {
                UAB ua;
                ua.u = *(const uint4*)(Ab + 32 * cc);
                acc0[rt] = __builtin_amdgcn_mfma_f32_32x32x16_bf16(
                               ua.s8, w0r[cc].s8, acc0[rt], 0, 0, 0);
                acc1[rt] = __builtin_amdgcn_mfma_f32_32x32x16_bf16(
                               ua.s8, w1r[cc].s8, acc1[rt], 0, 0, 0);
            }
        }

        // 4. pack + write next chunk
        if (ck + 1 < NCH) {
#pragma unroll
            for (int q = 0; q < 8; ++q) {
                uint2 o; o.x = cvtpk(v[q].x, v[q].y); o.y = cvtpk(v[q].z, v[q].w);
                *(uint2*)(nxt + wb_off + q * (16 * SROW)) = o;
            }
        }
        __syncthreads();
    }

    // ---- select per-row bucket: C elem (reg i, lane l) of row-tile rt:
    //      m = rt*32 + (i&3)+8*(i>>2)+4*(l>>5), n = l&31
    int bb0 = 2 * wv, bb1 = 2 * wv + 1;
#pragma unroll
    for (int rt = 0; rt < 4; ++rt) {
#pragma unroll
        for (int i = 0; i < 16; ++i) {
            int m = rt * 32 + (i & 3) + 8 * (i >> 2) + 4 * hi;
            int mb = bkt_s[m];
            if (mb == bb0 || mb == bb1) {
                float s = (mb == bb0) ? acc0[rt][i] : acc1[rt][i];
                float h = s + b0[mb * 32 + nn];
                hb[m * 36 + nn] = fminf(fmaxf(h, 0.0f), 1.0f);
            }
        }
    }
    __syncthreads();

    // ---- layers 1+2 (fp32): 2 threads per row (256 thr = 128 rows x 2)
    {
        int r = t >> 1, half = t & 1;
        int bkt = bkt_s[r];
        const float4* hr = (const float4*)(hb + r * 36);
        float4 ha[8];
#pragma unroll
        for (int q = 0; q < 8; ++q) ha[q] = hr[q];
        const float* w1b = w1 + (size_t)bkt * 1024;
        const float* b1b = b1 + bkt * 32;
        const float* w2b = w2 + bkt * 32;
        float partial = 0.0f;
#pragma unroll
        for (int jj = 0; jj < 16; ++jj) {
            int j2 = half * 16 + jj;
            const float4* wr = (const float4*)&w1b[j2 * 32];
            float s = b1b[j2];
#pragma unroll
            for (int q = 0; q < 8; ++q) {
                float4 w4 = wr[q];
                s += ha[q].x * w4.x + ha[q].y * w4.y + ha[q].z * w4.z + ha[q].w * w4.w;
            }
            s = fminf(fmaxf(s, 0.0f), 1.0f);
            partial += s * w2b[j2];
        }
        partial += __shfl_xor(partial, 1);
        if (half == 0) out[row0 + r] = partial + b2[bkt];
    }
}

// ---------------------------------------------------------------------------
extern "C" void kernel_launch(void* const* d_in, const int* in_sizes, int n_in,
                              void* d_out, int out_size, void* d_ws, size_t ws_size,
                              hipStream_t stream) {
    const float* x   = (const float*)d_in[0];
    const int*   lsi = (const int*)  d_in[1];
    const float* wf  = (const float*)d_in[2];
    const float* w0  = (const float*)d_in[3];
    const float* b0  = (const float*)d_in[4];
    const float* w1  = (const float*)d_in[5];
    const float* b1  = (const float*)d_in[6];
    const float* w2  = (const float*)d_in[7];
    const float* b2  = (const float*)d_in[8];
    float* out = (float*)d_out;

    char* ws = (char*)d_ws;
    uint4* wB = (uint4*)ws;
    unsigned char* bktg = (unsigned char*)(ws + BKT_OFF);

    k_prep<<<33, 1024, 0, stream>>>(lsi, w0, wf, wB, bktg);
    k_main<<<NBLK, 256, 0, stream>>>(x, bktg, wB, b0, w1, b1, w2, b2, out);
}